// Round 6
// baseline (418.913 us; speedup 1.0000x reference)
//
#include <hip/hip_runtime.h>
#include <stdint.h>

constexpr int NROWS = 1000000;
constexpr int D = 64;
constexpr int B = 64;
constexpr int TOPK = 5;
constexpr int TBLK = 4;      // per-block per-batch candidates kept
constexpr int TRES = 16;     // globally rescored candidates per batch
constexpr int NB2MAX = 2048; // 8 blocks/CU (48 VGPR, 4.2KB LDS -> 32 waves/CU)

typedef __attribute__((ext_vector_type(8))) short short8;
typedef __attribute__((ext_vector_type(4))) float floatx4;
typedef __attribute__((ext_vector_type(4))) unsigned uintx4;
typedef unsigned long long u64;

// workspace byte offsets
#define OFF_QKF   512      // qkf[64*64] f32   (16 KB)
#define OFF_QKB   16896    // qkb[64*64] bf16  (8 KB)
#define OFF_MM    25088    // minmax partials nb2*2 u32 (<= 32 KB)
#define OFF_CAND  57856    // cand[nb2*64*TBLK] u64

__device__ __forceinline__ unsigned fkey(float x) {
    unsigned u = __float_as_uint(x);
    return (u & 0x80000000u) ? ~u : (u | 0x80000000u);
}
__device__ __forceinline__ float fkey_inv(unsigned k) {
    unsigned u = (k & 0x80000000u) ? (k ^ 0x80000000u) : ~k;
    return __uint_as_float(u);
}
__device__ __forceinline__ unsigned short f2bf_rne(float x) {
    unsigned u = __float_as_uint(x);
    u += 0x7fffu + ((u >> 16) & 1u);
    return (unsigned short)(u >> 16);
}
// pack two f32 -> two bf16 (truncation; selection-only, exact rescore later)
__device__ __forceinline__ unsigned pack_bf16(float lo, float hi) {
    return (__float_as_uint(hi) & 0xFFFF0000u) | (__float_as_uint(lo) >> 16);
}

template<int K>
__device__ __forceinline__ void insert_key(u64 (&ks)[K], u64 key) {
    if (key > ks[K - 1]) {
        #pragma unroll
        for (int j = K - 1; j > 0; --j)
            ks[j] = (key > ks[j - 1]) ? ks[j - 1] : ((key > ks[j]) ? key : ks[j]);
        ks[0] = (key > ks[0]) ? key : ks[0];
    }
}

// branchless top-2 insert on u32 keys via v_min_u32/v_max_u32: a >= b invariant
__device__ __forceinline__ void insert2u(unsigned& a, unsigned& b, unsigned key) {
    unsigned lo = a < key ? a : key;
    unsigned hi = a < key ? key : a;
    a = hi;
    b = b < lo ? lo : b;
}

// u32 key (trunc-fkey[31:12] | (0xFFF - localRow)) -> global u64 cand key
__device__ __forceinline__ u64 expand_key(unsigned k32, int wbeg) {
    if (!k32) return 0ull;
    unsigned row = (unsigned)wbeg + (0xFFFu - (k32 & 0xFFFu));
    return ((u64)(k32 & 0xFFFFF000u) << 32) | (unsigned)~row;
}

// 16 blocks, 4 batches each: q = query@Wq^T, qk = q@Wk * 0.125.
__global__ void k_qk(const float* __restrict__ query, const float* __restrict__ Wq,
                     const float* __restrict__ Wk,
                     float* __restrict__ qkf, unsigned short* __restrict__ qkb) {
    __shared__ float q[4][64];
    int t = threadIdx.x;
    int b0 = blockIdx.x * 4;
    int bq = t >> 6, d = t & 63;
    float s1 = 0.f;
    for (int e = 0; e < 64; e++) s1 += query[(b0 + bq) * 64 + e] * Wq[d * 64 + e];
    q[bq][d] = s1;
    __syncthreads();
    float v = 0.f;
    for (int dd = 0; dd < 64; dd++) v += q[bq][dd] * Wk[dd * 64 + d];
    v *= 0.125f;
    qkf[(b0 + bq) * 64 + d] = v;
    qkb[(b0 + bq) * 64 + d] = f2bf_rne(v);
}

__device__ __forceinline__ void proc_tile(
        const float4& T0, const float4& T1, const float4& T2, const float4& T3,
        const float4& TA, int it, int qr,
        const short8 (&bq)[4][2], unsigned (&Ltop)[4], unsigned (&Lsec)[4],
        float& mnv, float& mxv) {
    // exact min/max on raw f32 (scale/zp must match reference)
    mnv = fminf(mnv, fminf(fminf(T0.x, T0.y), fminf(T0.z, T0.w)));
    mxv = fmaxf(mxv, fmaxf(fmaxf(T0.x, T0.y), fmaxf(T0.z, T0.w)));
    mnv = fminf(mnv, fminf(fminf(T1.x, T1.y), fminf(T1.z, T1.w)));
    mxv = fmaxf(mxv, fmaxf(fmaxf(T1.x, T1.y), fmaxf(T1.z, T1.w)));
    mnv = fminf(mnv, fminf(fminf(T2.x, T2.y), fminf(T2.z, T2.w)));
    mxv = fmaxf(mxv, fmaxf(fmaxf(T2.x, T2.y), fmaxf(T2.z, T2.w)));
    mnv = fminf(mnv, fminf(fminf(T3.x, T3.y), fminf(T3.z, T3.w)));
    mxv = fmaxf(mxv, fmaxf(fmaxf(T3.x, T3.y), fmaxf(T3.z, T3.w)));

    // bf16 A fragments via truncation-pack (byte-permute pattern)
    uintx4 ua0 = { pack_bf16(T0.x, T0.y), pack_bf16(T0.z, T0.w),
                   pack_bf16(T1.x, T1.y), pack_bf16(T1.z, T1.w) };
    uintx4 ua1 = { pack_bf16(T2.x, T2.y), pack_bf16(T2.z, T2.w),
                   pack_bf16(T3.x, T3.y), pack_bf16(T3.z, T3.w) };
    short8 a0 = __builtin_bit_cast(short8, ua0);
    short8 a1 = __builtin_bit_cast(short8, ua1);

    int idb = 0xFFF - it * 16 - qr;
    #pragma unroll
    for (int bt = 0; bt < 4; bt++) {
        floatx4 acc = {TA.x, TA.y, TA.z, TA.w};
        acc = __builtin_amdgcn_mfma_f32_16x16x32_bf16(a0, bq[bt][0], acc, 0, 0, 0);
        acc = __builtin_amdgcn_mfma_f32_16x16x32_bf16(a1, bq[bt][1], acc, 0, 0, 0);
        #pragma unroll
        for (int r = 0; r < 4; r++) {
            unsigned kk = (fkey(acc[r]) & 0xFFFFF000u) | (unsigned)(idb - r);
            insert2u(Ltop[bt], Lsec[bt], kk);
        }
    }
}

// Barrier-free scoring: each wave owns independent 16-row tiles, A-fragments
// loaded directly from global in fragment layout, converted in-register.
// Two statically-indexed tile register sets (A/B) alternate so each tile's
// loads are issued one full compute phase before their counted-vmcnt wait.
// Grid = 2048 blocks -> 8 blocks/CU, 32 waves/CU (latency hiding via TLP).
__launch_bounds__(256, 4)
__global__ void k_score_mm(const float* __restrict__ mem, const float* __restrict__ aw,
                           const unsigned short* __restrict__ qkb,
                           u64* __restrict__ cand,
                           unsigned* __restrict__ part, int wrows) {
    __shared__ u64 mrg[4][4][16][2];   // [wave][bt][l15][2] = 4 KB
    __shared__ float swmn[4], swmx[4];

    int t = threadIdx.x;
    int l15 = t & 15, quad = (t >> 4) & 3, w = t >> 6;
    int qr = quad * 4;

    // B fragments: B[k=quad*8+j][n=l15] from qkb[b][d]
    short8 bq[4][2];
    #pragma unroll
    for (int bt = 0; bt < 4; bt++) {
        #pragma unroll
        for (int kb = 0; kb < 2; kb++)
            bq[bt][kb] = *(const short8*)(qkb + (bt * 16 + l15) * 64 + kb * 32 + quad * 8);
    }

    unsigned Ltop[4], Lsec[4];
    #pragma unroll
    for (int bt = 0; bt < 4; bt++) { Ltop[bt] = 0u; Lsec[bt] = 0u; }

    float mnv = 3.402823466e38f, mxv = -3.402823466e38f;

    int gw = blockIdx.x * 4 + w;
    int wbeg = gw * wrows;
    int wend = min(wbeg + wrows, NROWS);
    int span = wend - wbeg;
    int nt = span > 0 ? (span >> 4) : 0;   // even: spans are multiples of 32 rows

    const char* pbase = (const char*)mem + (size_t)wbeg * 256 + (size_t)(l15 * 256 + quad * 32);
    const float* abase = aw + wbeg + qr;

    float4 A0, A1, A2, A3, AA, B0, B1, B2, B3, BA;

#define LOADT(T0, T1, T2, T3, TA, TILE) do {                                   \
        const char* pn_ = pbase + (size_t)(TILE) * 4096;                       \
        T0 = *(const float4*)(pn_);                                            \
        T1 = *(const float4*)(pn_ + 16);                                       \
        T2 = *(const float4*)(pn_ + 128);                                      \
        T3 = *(const float4*)(pn_ + 144);                                      \
        TA = *(const float4*)(abase + (TILE) * 16);                            \
    } while (0)

    if (nt > 0) {
        LOADT(A0, A1, A2, A3, AA, 0);
        for (int it = 0; it < nt; it += 2) {
            LOADT(B0, B1, B2, B3, BA, it + 1);
            proc_tile(A0, A1, A2, A3, AA, it, qr, bq, Ltop, Lsec, mnv, mxv);
            int nx = (it + 2 < nt) ? it + 2 : nt - 1;   // last iter re-load: harmless
            LOADT(A0, A1, A2, A3, AA, nx);
            proc_tile(B0, B1, B2, B3, BA, it + 1, qr, bq, Ltop, Lsec, mnv, mxv);
        }
    }
#undef LOADT

    // wave-level min/max reduce
    #pragma unroll
    for (int o = 32; o > 0; o >>= 1) {
        mnv = fminf(mnv, __shfl_xor(mnv, o));
        mxv = fmaxf(mxv, __shfl_xor(mxv, o));
    }
    if ((t & 63) == 0) { swmn[w] = mnv; swmx[w] = mxv; }

    // butterfly merge across quads: each (bt,l15) ends with wave-top-2
    #pragma unroll
    for (int bt = 0; bt < 4; bt++) {
        #pragma unroll
        for (int dlt = 16; dlt <= 32; dlt <<= 1) {
            unsigned ka = __shfl_xor(Ltop[bt], dlt);
            unsigned kb = __shfl_xor(Lsec[bt], dlt);
            insert2u(Ltop[bt], Lsec[bt], ka);
            insert2u(Ltop[bt], Lsec[bt], kb);
        }
    }
    if ((t & 48) == 0) {
        #pragma unroll
        for (int bt = 0; bt < 4; bt++) {
            mrg[w][bt][l15][0] = expand_key(Ltop[bt], wbeg);
            mrg[w][bt][l15][1] = expand_key(Lsec[bt], wbeg);
        }
    }
    __syncthreads();

    if (t == 0) {
        float a = fminf(fminf(swmn[0], swmn[1]), fminf(swmn[2], swmn[3]));
        float b2 = fmaxf(fmaxf(swmx[0], swmx[1]), fmaxf(swmx[2], swmx[3]));
        part[blockIdx.x * 2 + 0] = fkey(a);
        part[blockIdx.x * 2 + 1] = fkey(b2);
    }
    if (t < 64) {
        u64 ts[TBLK];
        #pragma unroll
        for (int j = 0; j < TBLK; j++) ts[j] = 0ull;
        int bt = t >> 4, l = t & 15;
        #pragma unroll
        for (int w2 = 0; w2 < 4; w2++) {
            insert_key<TBLK>(ts, mrg[w2][bt][l][0]);
            insert_key<TBLK>(ts, mrg[w2][bt][l][1]);
        }
        #pragma unroll
        for (int j = 0; j < TBLK; j++)
            cand[((long long)blockIdx.x * 64 + t) * TBLK + j] = ts[j];
    }
}

// One block per batch: reduce min/max partials -> scale/zp (overlapped with
// candidate gather), per-thread gated top-16 over strided candidates,
// 8-level pairwise sorted-merge tree, exact fp32 rescore of top-16, top-5,
// softmax, weighted dequant row sum, @ Wv^T.
__global__ void k_finalize(const u64* __restrict__ cand, int nb2,
                           const float* __restrict__ mem, const float* __restrict__ aw,
                           const float* __restrict__ Wv, const unsigned* __restrict__ part,
                           const float* __restrict__ qkf, float* __restrict__ out) {
    __shared__ u64 lists[256][TRES];   // 32 KB
    __shared__ float qkr[64];
    __shared__ int exid[TRES];
    __shared__ u64 exkey[TRES];
    __shared__ float exsc[TRES];
    __shared__ float wsel[TOPK];
    __shared__ int isel[TOPK];
    __shared__ float su[64];
    __shared__ unsigned redmn[4], redmx[4];
    __shared__ float sscale[2];

    int t = threadIdx.x, b = blockIdx.x;
    int total = nb2 * TBLK;

    // min/max partial reduction (independent of candidate gather)
    unsigned mnk = 0xFFFFFFFFu, mxk = 0u;
    for (int i = t; i < nb2; i += 256) {
        unsigned a = part[2 * i], c = part[2 * i + 1];
        mnk = a < mnk ? a : mnk;
        mxk = c > mxk ? c : mxk;
    }
    #pragma unroll
    for (int o = 32; o > 0; o >>= 1) {
        unsigned am = __shfl_xor(mnk, o); mnk = am < mnk ? am : mnk;
        unsigned ax = __shfl_xor(mxk, o); mxk = ax > mxk ? ax : mxk;
    }
    int w4 = t >> 6;
    if ((t & 63) == 0) { redmn[w4] = mnk; redmx[w4] = mxk; }

    u64 loc[TRES];
    #pragma unroll
    for (int j = 0; j < TRES; j++) loc[j] = 0ull;
    for (int i = t; i < total; i += 256) {
        int blk = i / TBLK, j = i - blk * TBLK;
        insert_key<TRES>(loc, cand[((long long)blk * 64 + b) * TBLK + j]);
    }
    #pragma unroll
    for (int j = 0; j < TRES; j++) lists[t][j] = loc[j];
    if (t < 64) qkr[t] = qkf[b * 64 + t];
    __syncthreads();

    // idle thread finalizes scale/zp
    if (t == 255) {
        unsigned m0 = redmn[0], M0 = redmx[0];
        #pragma unroll
        for (int i = 1; i < 4; i++) {
            m0 = redmn[i] < m0 ? redmn[i] : m0;
            M0 = redmx[i] > M0 ? redmx[i] : M0;
        }
        float mnv = fkey_inv(m0), mxv = fkey_inv(M0);
        float scale = (mxv - mnv) / 255.0f;
        sscale[0] = scale;
        sscale[1] = -mnv / scale;
    }

    for (int s = 128; s > 0; s >>= 1) {
        if (t < s) {
            #pragma unroll
            for (int j = 0; j < TRES; j++) insert_key<TRES>(loc, lists[t + s][j]);
            #pragma unroll
            for (int j = 0; j < TRES; j++) lists[t][j] = loc[j];
        }
        __syncthreads();
    }
    if (t < TRES) {
        u64 k = lists[0][t];
        exid[t] = k ? (int)(~(unsigned)k) : 0;
    }
    __syncthreads();

    float scale = sscale[0], zp = sscale[1];

    // exact rescore (mirrors reference: divide, rint, fp32)
    int lane = t & 63, w = t >> 6;
    for (int i = 0; i < 4; i++) {
        int c = w * 4 + i;
        int idx = exid[c];
        float m = mem[(long long)idx * 64 + lane];
        float dq = (rintf(m / scale + zp) - zp) * scale;
        float p2 = dq * qkr[lane];
        for (int o = 32; o > 0; o >>= 1) p2 += __shfl_xor(p2, o);
        if (lane == 0) {
            float ex = p2 + aw[idx];
            exsc[c] = ex;
            exkey[c] = ((u64)fkey(ex) << 32) | (unsigned)(~(unsigned)idx);
        }
    }
    __syncthreads();

    if (t == 0) {
        u64 bnd = ~0ull;
        float ssel[TOPK];
        for (int p = 0; p < TOPK; p++) {
            u64 best = 0ull; int bc = 0;
            for (int c = 0; c < TRES; c++) {
                u64 k = exkey[c];
                if (k < bnd && k > best) { best = k; bc = c; }
            }
            bnd = best;
            ssel[p] = exsc[bc];
            isel[p] = exid[bc];
        }
        float Z = 0.f;
        for (int p = 0; p < TOPK; p++) { wsel[p] = expf(ssel[p] - ssel[0]); Z += wsel[p]; }
        for (int p = 0; p < TOPK; p++) wsel[p] /= Z;
    }
    __syncthreads();

    if (t < 64) {
        float u = 0.f;
        #pragma unroll
        for (int p = 0; p < TOPK; p++) {
            float m = mem[(long long)isel[p] * 64 + t];
            float dq = (rintf(m / scale + zp) - zp) * scale;
            u += wsel[p] * dq;
        }
        su[t] = u;
    }
    __syncthreads();
    if (t < 64) {
        float o = 0.f;
        #pragma unroll
        for (int e = 0; e < 64; e++) o += su[e] * Wv[t * 64 + e];
        out[b * 64 + t] = o;
    }
}

extern "C" void kernel_launch(void* const* d_in, const int* in_sizes, int n_in,
                              void* d_out, int out_size, void* d_ws, size_t ws_size,
                              hipStream_t stream) {
    const float* query = (const float*)d_in[0];
    const float* mem   = (const float*)d_in[1];
    const float* aw    = (const float*)d_in[2];
    const float* Wq    = (const float*)d_in[3];
    const float* Wk    = (const float*)d_in[4];
    const float* Wv    = (const float*)d_in[5];
    float* out = (float*)d_out;

    char* ws = (char*)d_ws;
    float* qkf     = (float*)(ws + OFF_QKF);
    unsigned short* qkb = (unsigned short*)(ws + OFF_QKB);
    unsigned* part = (unsigned*)(ws + OFF_MM);
    u64* cand = (u64*)(ws + OFF_CAND);

    int nb2 = NB2MAX;
    size_t need = (size_t)OFF_CAND + (size_t)nb2 * 64 * TBLK * 8;
    if (ws_size < need) {
        size_t avail = ws_size > OFF_CAND ? ws_size - OFF_CAND : 0;
        nb2 = (int)(avail / ((size_t)64 * TBLK * 8));
        if (nb2 < 64) nb2 = 64;   // 12-bit local-row id requires wrows <= 4096
        if (nb2 > NB2MAX) nb2 = NB2MAX;
    }
    int waves = nb2 * 4;
    // 32-row multiple per wave -> per-wave tile count nt is even (NROWS % 32 == 0)
    int wrows = ((NROWS + waves - 1) / waves + 31) / 32 * 32;

    k_qk<<<16, 256, 0, stream>>>(query, Wq, Wk, qkf, qkb);
    k_score_mm<<<nb2, 256, 0, stream>>>(mem, aw, qkb, cand, part, wrows);
    k_finalize<<<B, 256, 0, stream>>>(cand, nb2, mem, aw, Wv, part, qkf, out);
}

// Round 7
// 414.561 us; speedup vs baseline: 1.0105x; 1.0105x over previous
//
#include <hip/hip_runtime.h>
#include <stdint.h>

constexpr int NROWS = 1000000;
constexpr int D = 64;
constexpr int B = 64;
constexpr int TOPK = 5;
constexpr int TBLK = 4;      // per-block per-batch candidates kept
constexpr int TRES = 16;     // globally rescored candidates per batch
constexpr int NB2MAX = 1024; // 4 blocks/CU (best-known grid; R6's 2048 was neutral)

typedef __attribute__((ext_vector_type(8))) short short8;
typedef __attribute__((ext_vector_type(4))) float floatx4;
typedef __attribute__((ext_vector_type(4))) unsigned uintx4;
typedef unsigned long long u64;

// workspace byte offsets
#define OFF_QKF   512      // qkf[64*64] f32   (16 KB)
#define OFF_QKB   16896    // qkb[64*64] bf16  (8 KB)
#define OFF_MM    25088    // minmax partials nb2*2 u32 (<= 32 KB)
#define OFF_CAND  57856    // cand[nb2*64*TBLK] u64

__device__ __forceinline__ unsigned fkey(float x) {
    unsigned u = __float_as_uint(x);
    return (u & 0x80000000u) ? ~u : (u | 0x80000000u);
}
__device__ __forceinline__ float fkey_inv(unsigned k) {
    unsigned u = (k & 0x80000000u) ? (k ^ 0x80000000u) : ~k;
    return __uint_as_float(u);
}
__device__ __forceinline__ unsigned short f2bf_rne(float x) {
    unsigned u = __float_as_uint(x);
    u += 0x7fffu + ((u >> 16) & 1u);
    return (unsigned short)(u >> 16);
}
// pack two f32 -> two bf16 (truncation; selection-only, exact rescore later)
__device__ __forceinline__ unsigned pack_bf16(float lo, float hi) {
    return (__float_as_uint(hi) & 0xFFFF0000u) | (__float_as_uint(lo) >> 16);
}

template<int K>
__device__ __forceinline__ void insert_key(u64 (&ks)[K], u64 key) {
    if (key > ks[K - 1]) {
        #pragma unroll
        for (int j = K - 1; j > 0; --j)
            ks[j] = (key > ks[j - 1]) ? ks[j - 1] : ((key > ks[j]) ? key : ks[j]);
        ks[0] = (key > ks[0]) ? key : ks[0];
    }
}

// branchless top-2 insert on u32 keys via v_min_u32/v_max_u32: a >= b invariant
__device__ __forceinline__ void insert2u(unsigned& a, unsigned& b, unsigned key) {
    unsigned lo = a < key ? a : key;
    unsigned hi = a < key ? key : a;
    a = hi;
    b = b < lo ? lo : b;
}

// u32 key (trunc-fkey[31:12] | (0xFFF - localRow)) -> global u64 cand key
__device__ __forceinline__ u64 expand_key(unsigned k32, int wbeg) {
    if (!k32) return 0ull;
    unsigned row = (unsigned)wbeg + (0xFFFu - (k32 & 0xFFFu));
    return ((u64)(k32 & 0xFFFFF000u) << 32) | (unsigned)~row;
}

// 16 blocks, 4 batches each: q = query@Wq^T, qk = q@Wk * 0.125.
__global__ void k_qk(const float* __restrict__ query, const float* __restrict__ Wq,
                     const float* __restrict__ Wk,
                     float* __restrict__ qkf, unsigned short* __restrict__ qkb) {
    __shared__ float q[4][64];
    int t = threadIdx.x;
    int b0 = blockIdx.x * 4;
    int bq = t >> 6, d = t & 63;
    float s1 = 0.f;
    for (int e = 0; e < 64; e++) s1 += query[(b0 + bq) * 64 + e] * Wq[d * 64 + e];
    q[bq][d] = s1;
    __syncthreads();
    float v = 0.f;
    for (int dd = 0; dd < 64; dd++) v += q[bq][dd] * Wk[dd * 64 + d];
    v *= 0.125f;
    qkf[(b0 + bq) * 64 + d] = v;
    qkb[(b0 + bq) * 64 + d] = f2bf_rne(v);
}

// k-permutation: lane quad q's MFMA k-slots {q*8+j} / {32+q*8+j} source f32
// elements {q*16+j} / {q*16+8+j}. Applied to BOTH A and B -> dot product
// invariant. A-side loads become ONE contiguous sector-aligned 64B run/lane.
__device__ __forceinline__ void proc_tile(
        const float4& T0, const float4& T1, const float4& T2, const float4& T3,
        const float4& TA, int it, int qr,
        const short8 (&bq)[4][2], unsigned (&Ltop)[4], unsigned (&Lsec)[4],
        float& mnv, float& mxv) {
    // exact min/max on raw f32 (scale/zp must match reference)
    mnv = fminf(mnv, fminf(fminf(T0.x, T0.y), fminf(T0.z, T0.w)));
    mxv = fmaxf(mxv, fmaxf(fmaxf(T0.x, T0.y), fmaxf(T0.z, T0.w)));
    mnv = fminf(mnv, fminf(fminf(T1.x, T1.y), fminf(T1.z, T1.w)));
    mxv = fmaxf(mxv, fmaxf(fmaxf(T1.x, T1.y), fmaxf(T1.z, T1.w)));
    mnv = fminf(mnv, fminf(fminf(T2.x, T2.y), fminf(T2.z, T2.w)));
    mxv = fmaxf(mxv, fmaxf(fmaxf(T2.x, T2.y), fmaxf(T2.z, T2.w)));
    mnv = fminf(mnv, fminf(fminf(T3.x, T3.y), fminf(T3.z, T3.w)));
    mxv = fmaxf(mxv, fmaxf(fmaxf(T3.x, T3.y), fmaxf(T3.z, T3.w)));

    // bf16 A fragments via truncation-pack:
    // a0 = elements q*16..+7 (T0,T1), a1 = q*16+8..+15 (T2,T3)
    uintx4 ua0 = { pack_bf16(T0.x, T0.y), pack_bf16(T0.z, T0.w),
                   pack_bf16(T1.x, T1.y), pack_bf16(T1.z, T1.w) };
    uintx4 ua1 = { pack_bf16(T2.x, T2.y), pack_bf16(T2.z, T2.w),
                   pack_bf16(T3.x, T3.y), pack_bf16(T3.z, T3.w) };
    short8 a0 = __builtin_bit_cast(short8, ua0);
    short8 a1 = __builtin_bit_cast(short8, ua1);

    int idb = 0xFFF - it * 16 - qr;
    #pragma unroll
    for (int bt = 0; bt < 4; bt++) {
        floatx4 acc = {TA.x, TA.y, TA.z, TA.w};
        acc = __builtin_amdgcn_mfma_f32_16x16x32_bf16(a0, bq[bt][0], acc, 0, 0, 0);
        acc = __builtin_amdgcn_mfma_f32_16x16x32_bf16(a1, bq[bt][1], acc, 0, 0, 0);
        #pragma unroll
        for (int r = 0; r < 4; r++) {
            unsigned kk = (fkey(acc[r]) & 0xFFFFF000u) | (unsigned)(idb - r);
            insert2u(Ltop[bt], Lsec[bt], kk);
        }
    }
}

// Barrier-free scoring: each wave owns independent 16-row tiles. Per lane, the
// tile's A-data is ONE contiguous 64B run (4 back-to-back dwordx4 into the same
// 64B sector -> MSHR-merged single line fetch; 4x fewer unique line requests
// than the previous stride-32/128 scatter). A/B register sets alternate so
// loads are issued one full compute phase before their counted-vmcnt wait.
__launch_bounds__(256, 4)
__global__ void k_score_mm(const float* __restrict__ mem, const float* __restrict__ aw,
                           const unsigned short* __restrict__ qkb,
                           u64* __restrict__ cand,
                           unsigned* __restrict__ part, int wrows) {
    __shared__ u64 mrg[4][4][16][2];   // [wave][bt][l15][2] = 4 KB
    __shared__ float swmn[4], swmx[4];

    int t = threadIdx.x;
    int l15 = t & 15, quad = (t >> 4) & 3, w = t >> 6;
    int qr = quad * 4;

    // B fragments under the same k-permutation:
    // b0[j] = qkb[bt*16+l15][quad*16+j], b1[j] = qkb[..][quad*16+8+j]
    short8 bq[4][2];
    #pragma unroll
    for (int bt = 0; bt < 4; bt++) {
        #pragma unroll
        for (int kb = 0; kb < 2; kb++)
            bq[bt][kb] = *(const short8*)(qkb + (bt * 16 + l15) * 64 + quad * 16 + kb * 8);
    }

    unsigned Ltop[4], Lsec[4];
    #pragma unroll
    for (int bt = 0; bt < 4; bt++) { Ltop[bt] = 0u; Lsec[bt] = 0u; }

    float mnv = 3.402823466e38f, mxv = -3.402823466e38f;

    int gw = blockIdx.x * 4 + w;
    int wbeg = gw * wrows;
    int wend = min(wbeg + wrows, NROWS);
    int span = wend - wbeg;
    int nt = span > 0 ? (span >> 4) : 0;   // even: spans are multiples of 32 rows

    // lane (l15, quad): row l15, bytes quad*64 .. +63 (one 64B sector)
    const char* pbase = (const char*)mem + (size_t)wbeg * 256 + (size_t)(l15 * 256 + quad * 64);
    const float* abase = aw + wbeg + qr;

    float4 A0, A1, A2, A3, AA, B0, B1, B2, B3, BA;

#define LOADT(T0, T1, T2, T3, TA, TILE) do {                                   \
        const char* pn_ = pbase + (size_t)(TILE) * 4096;                       \
        T0 = *(const float4*)(pn_);                                            \
        T1 = *(const float4*)(pn_ + 16);                                       \
        T2 = *(const float4*)(pn_ + 32);                                       \
        T3 = *(const float4*)(pn_ + 48);                                       \
        TA = *(const float4*)(abase + (TILE) * 16);                            \
    } while (0)

    if (nt > 0) {
        LOADT(A0, A1, A2, A3, AA, 0);
        for (int it = 0; it < nt; it += 2) {
            LOADT(B0, B1, B2, B3, BA, it + 1);
            proc_tile(A0, A1, A2, A3, AA, it, qr, bq, Ltop, Lsec, mnv, mxv);
            int nx = (it + 2 < nt) ? it + 2 : nt - 1;   // last iter re-load: harmless
            LOADT(A0, A1, A2, A3, AA, nx);
            proc_tile(B0, B1, B2, B3, BA, it + 1, qr, bq, Ltop, Lsec, mnv, mxv);
        }
    }
#undef LOADT

    // wave-level min/max reduce
    #pragma unroll
    for (int o = 32; o > 0; o >>= 1) {
        mnv = fminf(mnv, __shfl_xor(mnv, o));
        mxv = fmaxf(mxv, __shfl_xor(mxv, o));
    }
    if ((t & 63) == 0) { swmn[w] = mnv; swmx[w] = mxv; }

    // butterfly merge across quads: each (bt,l15) ends with wave-top-2
    #pragma unroll
    for (int bt = 0; bt < 4; bt++) {
        #pragma unroll
        for (int dlt = 16; dlt <= 32; dlt <<= 1) {
            unsigned ka = __shfl_xor(Ltop[bt], dlt);
            unsigned kb = __shfl_xor(Lsec[bt], dlt);
            insert2u(Ltop[bt], Lsec[bt], ka);
            insert2u(Ltop[bt], Lsec[bt], kb);
        }
    }
    if ((t & 48) == 0) {
        #pragma unroll
        for (int bt = 0; bt < 4; bt++) {
            mrg[w][bt][l15][0] = expand_key(Ltop[bt], wbeg);
            mrg[w][bt][l15][1] = expand_key(Lsec[bt], wbeg);
        }
    }
    __syncthreads();

    if (t == 0) {
        float a = fminf(fminf(swmn[0], swmn[1]), fminf(swmn[2], swmn[3]));
        float b2 = fmaxf(fmaxf(swmx[0], swmx[1]), fmaxf(swmx[2], swmx[3]));
        part[blockIdx.x * 2 + 0] = fkey(a);
        part[blockIdx.x * 2 + 1] = fkey(b2);
    }
    if (t < 64) {
        u64 ts[TBLK];
        #pragma unroll
        for (int j = 0; j < TBLK; j++) ts[j] = 0ull;
        int bt = t >> 4, l = t & 15;
        #pragma unroll
        for (int w2 = 0; w2 < 4; w2++) {
            insert_key<TBLK>(ts, mrg[w2][bt][l][0]);
            insert_key<TBLK>(ts, mrg[w2][bt][l][1]);
        }
        #pragma unroll
        for (int j = 0; j < TBLK; j++)
            cand[((long long)blockIdx.x * 64 + t) * TBLK + j] = ts[j];
    }
}

// One block per batch: reduce min/max partials -> scale/zp (overlapped with
// candidate gather), per-thread gated top-16 over strided candidates,
// 8-level pairwise sorted-merge tree, exact fp32 rescore of top-16, top-5,
// softmax, weighted dequant row sum, @ Wv^T.
__global__ void k_finalize(const u64* __restrict__ cand, int nb2,
                           const float* __restrict__ mem, const float* __restrict__ aw,
                           const float* __restrict__ Wv, const unsigned* __restrict__ part,
                           const float* __restrict__ qkf, float* __restrict__ out) {
    __shared__ u64 lists[256][TRES];   // 32 KB
    __shared__ float qkr[64];
    __shared__ int exid[TRES];
    __shared__ u64 exkey[TRES];
    __shared__ float exsc[TRES];
    __shared__ float wsel[TOPK];
    __shared__ int isel[TOPK];
    __shared__ float su[64];
    __shared__ unsigned redmn[4], redmx[4];
    __shared__ float sscale[2];

    int t = threadIdx.x, b = blockIdx.x;
    int total = nb2 * TBLK;

    // min/max partial reduction (independent of candidate gather)
    unsigned mnk = 0xFFFFFFFFu, mxk = 0u;
    for (int i = t; i < nb2; i += 256) {
        unsigned a = part[2 * i], c = part[2 * i + 1];
        mnk = a < mnk ? a : mnk;
        mxk = c > mxk ? c : mxk;
    }
    #pragma unroll
    for (int o = 32; o > 0; o >>= 1) {
        unsigned am = __shfl_xor(mnk, o); mnk = am < mnk ? am : mnk;
        unsigned ax = __shfl_xor(mxk, o); mxk = ax > mxk ? ax : mxk;
    }
    int w4 = t >> 6;
    if ((t & 63) == 0) { redmn[w4] = mnk; redmx[w4] = mxk; }

    u64 loc[TRES];
    #pragma unroll
    for (int j = 0; j < TRES; j++) loc[j] = 0ull;
    for (int i = t; i < total; i += 256) {
        int blk = i / TBLK, j = i - blk * TBLK;
        insert_key<TRES>(loc, cand[((long long)blk * 64 + b) * TBLK + j]);
    }
    #pragma unroll
    for (int j = 0; j < TRES; j++) lists[t][j] = loc[j];
    if (t < 64) qkr[t] = qkf[b * 64 + t];
    __syncthreads();

    // idle thread finalizes scale/zp
    if (t == 255) {
        unsigned m0 = redmn[0], M0 = redmx[0];
        #pragma unroll
        for (int i = 1; i < 4; i++) {
            m0 = redmn[i] < m0 ? redmn[i] : m0;
            M0 = redmx[i] > M0 ? redmx[i] : M0;
        }
        float mnv = fkey_inv(m0), mxv = fkey_inv(M0);
        float scale = (mxv - mnv) / 255.0f;
        sscale[0] = scale;
        sscale[1] = -mnv / scale;
    }

    for (int s = 128; s > 0; s >>= 1) {
        if (t < s) {
            #pragma unroll
            for (int j = 0; j < TRES; j++) insert_key<TRES>(loc, lists[t + s][j]);
            #pragma unroll
            for (int j = 0; j < TRES; j++) lists[t][j] = loc[j];
        }
        __syncthreads();
    }
    if (t < TRES) {
        u64 k = lists[0][t];
        exid[t] = k ? (int)(~(unsigned)k) : 0;
    }
    __syncthreads();

    float scale = sscale[0], zp = sscale[1];

    // exact rescore (mirrors reference: divide, rint, fp32)
    int lane = t & 63, w = t >> 6;
    for (int i = 0; i < 4; i++) {
        int c = w * 4 + i;
        int idx = exid[c];
        float m = mem[(long long)idx * 64 + lane];
        float dq = (rintf(m / scale + zp) - zp) * scale;
        float p2 = dq * qkr[lane];
        for (int o = 32; o > 0; o >>= 1) p2 += __shfl_xor(p2, o);
        if (lane == 0) {
            float ex = p2 + aw[idx];
            exsc[c] = ex;
            exkey[c] = ((u64)fkey(ex) << 32) | (unsigned)(~(unsigned)idx);
        }
    }
    __syncthreads();

    if (t == 0) {
        u64 bnd = ~0ull;
        float ssel[TOPK];
        for (int p = 0; p < TOPK; p++) {
            u64 best = 0ull; int bc = 0;
            for (int c = 0; c < TRES; c++) {
                u64 k = exkey[c];
                if (k < bnd && k > best) { best = k; bc = c; }
            }
            bnd = best;
            ssel[p] = exsc[bc];
            isel[p] = exid[bc];
        }
        float Z = 0.f;
        for (int p = 0; p < TOPK; p++) { wsel[p] = expf(ssel[p] - ssel[0]); Z += wsel[p]; }
        for (int p = 0; p < TOPK; p++) wsel[p] /= Z;
    }
    __syncthreads();

    if (t < 64) {
        float u = 0.f;
        #pragma unroll
        for (int p = 0; p < TOPK; p++) {
            float m = mem[(long long)isel[p] * 64 + t];
            float dq = (rintf(m / scale + zp) - zp) * scale;
            u += wsel[p] * dq;
        }
        su[t] = u;
    }
    __syncthreads();
    if (t < 64) {
        float o = 0.f;
        #pragma unroll
        for (int e = 0; e < 64; e++) o += su[e] * Wv[t * 64 + e];
        out[b * 64 + t] = o;
    }
}

extern "C" void kernel_launch(void* const* d_in, const int* in_sizes, int n_in,
                              void* d_out, int out_size, void* d_ws, size_t ws_size,
                              hipStream_t stream) {
    const float* query = (const float*)d_in[0];
    const float* mem   = (const float*)d_in[1];
    const float* aw    = (const float*)d_in[2];
    const float* Wq    = (const float*)d_in[3];
    const float* Wk    = (const float*)d_in[4];
    const float* Wv    = (const float*)d_in[5];
    float* out = (float*)d_out;

    char* ws = (char*)d_ws;
    float* qkf     = (float*)(ws + OFF_QKF);
    unsigned short* qkb = (unsigned short*)(ws + OFF_QKB);
    unsigned* part = (unsigned*)(ws + OFF_MM);
    u64* cand = (u64*)(ws + OFF_CAND);

    int nb2 = NB2MAX;
    size_t need = (size_t)OFF_CAND + (size_t)nb2 * 64 * TBLK * 8;
    if (ws_size < need) {
        size_t avail = ws_size > OFF_CAND ? ws_size - OFF_CAND : 0;
        nb2 = (int)(avail / ((size_t)64 * TBLK * 8));
        if (nb2 < 64) nb2 = 64;   // 12-bit local-row id requires wrows <= 4096
        if (nb2 > NB2MAX) nb2 = NB2MAX;
    }
    int waves = nb2 * 4;
    // 32-row multiple per wave -> per-wave tile count nt is even (NROWS % 32 == 0)
    int wrows = ((NROWS + waves - 1) / waves + 31) / 32 * 32;

    k_qk<<<16, 256, 0, stream>>>(query, Wq, Wk, qkf, qkb);
    k_score_mm<<<nb2, 256, 0, stream>>>(mem, aw, qkb, cand, part, wrows);
    k_finalize<<<B, 256, 0, stream>>>(cand, nb2, mem, aw, Wv, part, qkf, out);
}

// Round 8
// 408.545 us; speedup vs baseline: 1.0254x; 1.0147x over previous
//
#include <hip/hip_runtime.h>
#include <stdint.h>

constexpr int NROWS = 1000000;
constexpr int D = 64;
constexpr int B = 64;
constexpr int TOPK = 5;
constexpr int TBLK = 4;      // per-block per-batch candidates kept
constexpr int TRES = 16;     // globally rescored candidates per batch
constexpr int NB2MAX = 768;  // 3 blocks/CU exactly (launch_bounds (256,3) -> VGPR cap 170)

typedef __attribute__((ext_vector_type(8))) short short8;
typedef __attribute__((ext_vector_type(4))) float floatx4;
typedef __attribute__((ext_vector_type(4))) unsigned uintx4;
typedef unsigned long long u64;

// workspace byte offsets
#define OFF_QKF   512      // qkf[64*64] f32   (16 KB)
#define OFF_QKB   16896    // qkb[64*64] bf16  (8 KB)
#define OFF_MM    25088    // minmax partials nb2*2 u32 (<= 32 KB)
#define OFF_CAND  57856    // cand[64*nb2*TBLK] u64 (batch-major for coalesced gather)

__device__ __forceinline__ unsigned fkey(float x) {
    unsigned u = __float_as_uint(x);
    return (u & 0x80000000u) ? ~u : (u | 0x80000000u);
}
__device__ __forceinline__ float fkey_inv(unsigned k) {
    unsigned u = (k & 0x80000000u) ? (k ^ 0x80000000u) : ~k;
    return __uint_as_float(u);
}
__device__ __forceinline__ unsigned short f2bf_rne(float x) {
    unsigned u = __float_as_uint(x);
    u += 0x7fffu + ((u >> 16) & 1u);
    return (unsigned short)(u >> 16);
}
// pack two f32 -> two bf16 (truncation; selection-only, exact rescore later)
__device__ __forceinline__ unsigned pack_bf16(float lo, float hi) {
    return (__float_as_uint(hi) & 0xFFFF0000u) | (__float_as_uint(lo) >> 16);
}

template<int K>
__device__ __forceinline__ void insert_key(u64 (&ks)[K], u64 key) {
    if (key > ks[K - 1]) {
        #pragma unroll
        for (int j = K - 1; j > 0; --j)
            ks[j] = (key > ks[j - 1]) ? ks[j - 1] : ((key > ks[j]) ? key : ks[j]);
        ks[0] = (key > ks[0]) ? key : ks[0];
    }
}

// branchless top-2 insert on u32 keys via v_min_u32/v_max_u32: a >= b invariant
__device__ __forceinline__ void insert2u(unsigned& a, unsigned& b, unsigned key) {
    unsigned lo = a < key ? a : key;
    unsigned hi = a < key ? key : a;
    a = hi;
    b = b < lo ? lo : b;
}

// u32 key (trunc-fkey[31:12] | (0xFFF - localRow)) -> global u64 cand key
__device__ __forceinline__ u64 expand_key(unsigned k32, int wbeg) {
    if (!k32) return 0ull;
    unsigned row = (unsigned)wbeg + (0xFFFu - (k32 & 0xFFFu));
    return ((u64)(k32 & 0xFFFFF000u) << 32) | (unsigned)~row;
}

// 16 blocks, 4 batches each: q = query@Wq^T, qk = q@Wk * 0.125.
// Wq staged in LDS (coalesced) to kill the d-major stride-64 gather; the Wk
// pass reads Wk[dd*64+d] which is already lane-coalesced from global.
__global__ void k_qk(const float* __restrict__ query, const float* __restrict__ Wq,
                     const float* __restrict__ Wk,
                     float* __restrict__ qkf, unsigned short* __restrict__ qkb) {
    __shared__ float wq[64][65];   // +1 pad: 2-way bank alias only (free)
    __shared__ float q[4][64];
    int t = threadIdx.x;
    int b0 = blockIdx.x * 4;
    int bq = t >> 6, d = t & 63;

    #pragma unroll
    for (int i = 0; i < 4; i++) {
        int flat = (i * 256 + t) * 4;            // coalesced float4 loads of Wq
        float4 v = *(const float4*)(Wq + flat);
        int r = flat >> 6, c = flat & 63;
        wq[r][c + 0] = v.x; wq[r][c + 1] = v.y;
        wq[r][c + 2] = v.z; wq[r][c + 3] = v.w;
    }
    __syncthreads();

    float s1 = 0.f;
    for (int e = 0; e < 64; e++) s1 += query[(b0 + bq) * 64 + e] * wq[d][e];
    q[bq][d] = s1;
    __syncthreads();
    float v = 0.f;
    for (int dd = 0; dd < 64; dd++) v += q[bq][dd] * Wk[dd * 64 + d];
    v *= 0.125f;
    qkf[(b0 + bq) * 64 + d] = v;
    qkb[(b0 + bq) * 64 + d] = f2bf_rne(v);
}

// k-permutation: lane quad q's MFMA k-slots source f32 elements {q*16..+15}.
// Applied to BOTH A and B -> dot product invariant. Per-lane A-data is one
// contiguous 64B sector. Two INDEPENDENT accumulators per batch-tile (second
// seeded 0, summed at key build) so the MFMA chain never serializes against
// the score consumer.
__device__ __forceinline__ void proc_tile(
        const float4& T0, const float4& T1, const float4& T2, const float4& T3,
        const float4& TA, int it, int qr,
        const short8 (&bq)[4][2], unsigned (&Ltop)[4], unsigned (&Lsec)[4],
        float& mnv, float& mxv) {
    // exact min/max on raw f32 (scale/zp must match reference)
    mnv = fminf(mnv, fminf(fminf(T0.x, T0.y), fminf(T0.z, T0.w)));
    mxv = fmaxf(mxv, fmaxf(fmaxf(T0.x, T0.y), fmaxf(T0.z, T0.w)));
    mnv = fminf(mnv, fminf(fminf(T1.x, T1.y), fminf(T1.z, T1.w)));
    mxv = fmaxf(mxv, fmaxf(fmaxf(T1.x, T1.y), fmaxf(T1.z, T1.w)));
    mnv = fminf(mnv, fminf(fminf(T2.x, T2.y), fminf(T2.z, T2.w)));
    mxv = fmaxf(mxv, fmaxf(fmaxf(T2.x, T2.y), fmaxf(T2.z, T2.w)));
    mnv = fminf(mnv, fminf(fminf(T3.x, T3.y), fminf(T3.z, T3.w)));
    mxv = fmaxf(mxv, fmaxf(fmaxf(T3.x, T3.y), fmaxf(T3.z, T3.w)));

    // bf16 A fragments via truncation-pack:
    // a0 = elements q*16..+7 (T0,T1), a1 = q*16+8..+15 (T2,T3)
    uintx4 ua0 = { pack_bf16(T0.x, T0.y), pack_bf16(T0.z, T0.w),
                   pack_bf16(T1.x, T1.y), pack_bf16(T1.z, T1.w) };
    uintx4 ua1 = { pack_bf16(T2.x, T2.y), pack_bf16(T2.z, T2.w),
                   pack_bf16(T3.x, T3.y), pack_bf16(T3.z, T3.w) };
    short8 a0 = __builtin_bit_cast(short8, ua0);
    short8 a1 = __builtin_bit_cast(short8, ua1);

    floatx4 zero = {0.f, 0.f, 0.f, 0.f};
    int idb = 0xFFF - it * 16 - qr;
    #pragma unroll
    for (int bt = 0; bt < 4; bt++) {
        floatx4 acc0 = {TA.x, TA.y, TA.z, TA.w};
        acc0 = __builtin_amdgcn_mfma_f32_16x16x32_bf16(a0, bq[bt][0], acc0, 0, 0, 0);
        floatx4 acc1 = __builtin_amdgcn_mfma_f32_16x16x32_bf16(a1, bq[bt][1], zero, 0, 0, 0);
        #pragma unroll
        for (int r = 0; r < 4; r++) {
            unsigned kk = (fkey(acc0[r] + acc1[r]) & 0xFFFFF000u) | (unsigned)(idb - r);
            insert2u(Ltop[bt], Lsec[bt], kk);
        }
    }
}

// Barrier-free scoring: each wave owns independent 16-row tiles, A-fragments
// loaded directly from global in fragment layout, converted in-register.
// A/B register tile sets alternate (loads issued one compute phase ahead).
// launch_bounds (256,3): VGPR cap 170 so the ~120-reg working set (2 tile
// sets + 32-reg B fragments) fits WITHOUT scratch spills (the R3 cliff, and
// the suspected hidden cost at the previous (256,4)=128 cap).
__launch_bounds__(256, 3)
__global__ void k_score_mm(const float* __restrict__ mem, const float* __restrict__ aw,
                           const unsigned short* __restrict__ qkb,
                           u64* __restrict__ cand, int nb2,
                           unsigned* __restrict__ part, int wrows) {
    __shared__ u64 mrg[4][4][16][2];   // [wave][bt][l15][2] = 4 KB
    __shared__ float swmn[4], swmx[4];

    int t = threadIdx.x;
    int l15 = t & 15, quad = (t >> 4) & 3, w = t >> 6;
    int qr = quad * 4;

    // B fragments under the same k-permutation:
    // b0[j] = qkb[bt*16+l15][quad*16+j], b1[j] = qkb[..][quad*16+8+j]
    short8 bq[4][2];
    #pragma unroll
    for (int bt = 0; bt < 4; bt++) {
        #pragma unroll
        for (int kb = 0; kb < 2; kb++)
            bq[bt][kb] = *(const short8*)(qkb + (bt * 16 + l15) * 64 + quad * 16 + kb * 8);
    }

    unsigned Ltop[4], Lsec[4];
    #pragma unroll
    for (int bt = 0; bt < 4; bt++) { Ltop[bt] = 0u; Lsec[bt] = 0u; }

    float mnv = 3.402823466e38f, mxv = -3.402823466e38f;

    int gw = blockIdx.x * 4 + w;
    int wbeg = gw * wrows;
    int wend = min(wbeg + wrows, NROWS);
    int span = wend - wbeg;
    int nt = span > 0 ? (span >> 4) : 0;   // even: spans are multiples of 32 rows

    // lane (l15, quad): row l15, bytes quad*64 .. +63 (one 64B sector)
    const char* pbase = (const char*)mem + (size_t)wbeg * 256 + (size_t)(l15 * 256 + quad * 64);
    const float* abase = aw + wbeg + qr;

    float4 A0, A1, A2, A3, AA, B0, B1, B2, B3, BA;

#define LOADT(T0, T1, T2, T3, TA, TILE) do {                                   \
        const char* pn_ = pbase + (size_t)(TILE) * 4096;                       \
        T0 = *(const float4*)(pn_);                                            \
        T1 = *(const float4*)(pn_ + 16);                                       \
        T2 = *(const float4*)(pn_ + 32);                                       \
        T3 = *(const float4*)(pn_ + 48);                                       \
        TA = *(const float4*)(abase + (TILE) * 16);                            \
    } while (0)

    if (nt > 0) {
        LOADT(A0, A1, A2, A3, AA, 0);
        for (int it = 0; it < nt; it += 2) {
            LOADT(B0, B1, B2, B3, BA, it + 1);
            proc_tile(A0, A1, A2, A3, AA, it, qr, bq, Ltop, Lsec, mnv, mxv);
            int nx = (it + 2 < nt) ? it + 2 : nt - 1;   // last iter re-load: harmless
            LOADT(A0, A1, A2, A3, AA, nx);
            proc_tile(B0, B1, B2, B3, BA, it + 1, qr, bq, Ltop, Lsec, mnv, mxv);
        }
    }
#undef LOADT

    // wave-level min/max reduce
    #pragma unroll
    for (int o = 32; o > 0; o >>= 1) {
        mnv = fminf(mnv, __shfl_xor(mnv, o));
        mxv = fmaxf(mxv, __shfl_xor(mxv, o));
    }
    if ((t & 63) == 0) { swmn[w] = mnv; swmx[w] = mxv; }

    // butterfly merge across quads: each (bt,l15) ends with wave-top-2
    #pragma unroll
    for (int bt = 0; bt < 4; bt++) {
        #pragma unroll
        for (int dlt = 16; dlt <= 32; dlt <<= 1) {
            unsigned ka = __shfl_xor(Ltop[bt], dlt);
            unsigned kb = __shfl_xor(Lsec[bt], dlt);
            insert2u(Ltop[bt], Lsec[bt], ka);
            insert2u(Ltop[bt], Lsec[bt], kb);
        }
    }
    if ((t & 48) == 0) {
        #pragma unroll
        for (int bt = 0; bt < 4; bt++) {
            mrg[w][bt][l15][0] = expand_key(Ltop[bt], wbeg);
            mrg[w][bt][l15][1] = expand_key(Lsec[bt], wbeg);
        }
    }
    __syncthreads();

    if (t == 0) {
        float a = fminf(fminf(swmn[0], swmn[1]), fminf(swmn[2], swmn[3]));
        float b2 = fmaxf(fmaxf(swmx[0], swmx[1]), fmaxf(swmx[2], swmx[3]));
        part[blockIdx.x * 2 + 0] = fkey(a);
        part[blockIdx.x * 2 + 1] = fkey(b2);
    }
    if (t < 64) {
        u64 ts[TBLK];
        #pragma unroll
        for (int j = 0; j < TBLK; j++) ts[j] = 0ull;
        int bt = t >> 4, l = t & 15;
        #pragma unroll
        for (int w2 = 0; w2 < 4; w2++) {
            insert_key<TBLK>(ts, mrg[w2][bt][l][0]);
            insert_key<TBLK>(ts, mrg[w2][bt][l][1]);
        }
        // batch-major layout: cand[(batch*nb2 + block)*TBLK + j] -> finalize
        // gathers are fully coalesced
        #pragma unroll
        for (int j = 0; j < TBLK; j++)
            cand[((long long)t * nb2 + blockIdx.x) * TBLK + j] = ts[j];
    }
}

// One block per batch: reduce min/max partials -> scale/zp (overlapped with
// candidate gather), per-thread gated top-16 over COALESCED batch-major
// candidates, 8-level pairwise sorted-merge tree, exact fp32 rescore of
// top-16, top-5, softmax, weighted dequant row sum, @ Wv^T.
__global__ void k_finalize(const u64* __restrict__ cand, int nb2,
                           const float* __restrict__ mem, const float* __restrict__ aw,
                           const float* __restrict__ Wv, const unsigned* __restrict__ part,
                           const float* __restrict__ qkf, float* __restrict__ out) {
    __shared__ u64 lists[256][TRES];   // 32 KB
    __shared__ float qkr[64];
    __shared__ int exid[TRES];
    __shared__ u64 exkey[TRES];
    __shared__ float exsc[TRES];
    __shared__ float wsel[TOPK];
    __shared__ int isel[TOPK];
    __shared__ float su[64];
    __shared__ unsigned redmn[4], redmx[4];
    __shared__ float sscale[2];

    int t = threadIdx.x, b = blockIdx.x;
    int total = nb2 * TBLK;

    // min/max partial reduction (independent of candidate gather)
    unsigned mnk = 0xFFFFFFFFu, mxk = 0u;
    for (int i = t; i < nb2; i += 256) {
        unsigned a = part[2 * i], c = part[2 * i + 1];
        mnk = a < mnk ? a : mnk;
        mxk = c > mxk ? c : mxk;
    }
    #pragma unroll
    for (int o = 32; o > 0; o >>= 1) {
        unsigned am = __shfl_xor(mnk, o); mnk = am < mnk ? am : mnk;
        unsigned ax = __shfl_xor(mxk, o); mxk = ax > mxk ? ax : mxk;
    }
    int w4 = t >> 6;
    if ((t & 63) == 0) { redmn[w4] = mnk; redmx[w4] = mxk; }

    const u64* cb = cand + (long long)b * total;   // batch-major: contiguous
    u64 loc[TRES];
    #pragma unroll
    for (int j = 0; j < TRES; j++) loc[j] = 0ull;
    for (int i = t; i < total; i += 256)
        insert_key<TRES>(loc, cb[i]);
    #pragma unroll
    for (int j = 0; j < TRES; j++) lists[t][j] = loc[j];
    if (t < 64) qkr[t] = qkf[b * 64 + t];
    __syncthreads();

    // idle thread finalizes scale/zp
    if (t == 255) {
        unsigned m0 = redmn[0], M0 = redmx[0];
        #pragma unroll
        for (int i = 1; i < 4; i++) {
            m0 = redmn[i] < m0 ? redmn[i] : m0;
            M0 = redmx[i] > M0 ? redmx[i] : M0;
        }
        float mnv = fkey_inv(m0), mxv = fkey_inv(M0);
        float scale = (mxv - mnv) / 255.0f;
        sscale[0] = scale;
        sscale[1] = -mnv / scale;
    }

    for (int s = 128; s > 0; s >>= 1) {
        if (t < s) {
            #pragma unroll
            for (int j = 0; j < TRES; j++) insert_key<TRES>(loc, lists[t + s][j]);
            #pragma unroll
            for (int j = 0; j < TRES; j++) lists[t][j] = loc[j];
        }
        __syncthreads();
    }
    if (t < TRES) {
        u64 k = lists[0][t];
        exid[t] = k ? (int)(~(unsigned)k) : 0;
    }
    __syncthreads();

    float scale = sscale[0], zp = sscale[1];

    // exact rescore (mirrors reference: divide, rint, fp32)
    int lane = t & 63, w = t >> 6;
    for (int i = 0; i < 4; i++) {
        int c = w * 4 + i;
        int idx = exid[c];
        float m = mem[(long long)idx * 64 + lane];
        float dq = (rintf(m / scale + zp) - zp) * scale;
        float p2 = dq * qkr[lane];
        for (int o = 32; o > 0; o >>= 1) p2 += __shfl_xor(p2, o);
        if (lane == 0) {
            float ex = p2 + aw[idx];
            exsc[c] = ex;
            exkey[c] = ((u64)fkey(ex) << 32) | (unsigned)(~(unsigned)idx);
        }
    }
    __syncthreads();

    if (t == 0) {
        u64 bnd = ~0ull;
        float ssel[TOPK];
        for (int p = 0; p < TOPK; p++) {
            u64 best = 0ull; int bc = 0;
            for (int c = 0; c < TRES; c++) {
                u64 k = exkey[c];
                if (k < bnd && k > best) { best = k; bc = c; }
            }
            bnd = best;
            ssel[p] = exsc[bc];
            isel[p] = exid[bc];
        }
        float Z = 0.f;
        for (int p = 0; p < TOPK; p++) { wsel[p] = expf(ssel[p] - ssel[0]); Z += wsel[p]; }
        for (int p = 0; p < TOPK; p++) wsel[p] /= Z;
    }
    __syncthreads();

    if (t < 64) {
        float u = 0.f;
        #pragma unroll
        for (int p = 0; p < TOPK; p++) {
            float m = mem[(long long)isel[p] * 64 + t];
            float dq = (rintf(m / scale + zp) - zp) * scale;
            u += wsel[p] * dq;
        }
        su[t] = u;
    }
    __syncthreads();
    if (t < 64) {
        float o = 0.f;
        #pragma unroll
        for (int e = 0; e < 64; e++) o += su[e] * Wv[t * 64 + e];
        out[b * 64 + t] = o;
    }
}

extern "C" void kernel_launch(void* const* d_in, const int* in_sizes, int n_in,
                              void* d_out, int out_size, void* d_ws, size_t ws_size,
                              hipStream_t stream) {
    const float* query = (const float*)d_in[0];
    const float* mem   = (const float*)d_in[1];
    const float* aw    = (const float*)d_in[2];
    const float* Wq    = (const float*)d_in[3];
    const float* Wk    = (const float*)d_in[4];
    const float* Wv    = (const float*)d_in[5];
    float* out = (float*)d_out;

    char* ws = (char*)d_ws;
    float* qkf     = (float*)(ws + OFF_QKF);
    unsigned short* qkb = (unsigned short*)(ws + OFF_QKB);
    unsigned* part = (unsigned*)(ws + OFF_MM);
    u64* cand = (u64*)(ws + OFF_CAND);

    int nb2 = NB2MAX;
    size_t need = (size_t)OFF_CAND + (size_t)nb2 * 64 * TBLK * 8;
    if (ws_size < need) {
        size_t avail = ws_size > OFF_CAND ? ws_size - OFF_CAND : 0;
        nb2 = (int)(avail / ((size_t)64 * TBLK * 8));
        if (nb2 < 64) nb2 = 64;   // 12-bit local-row id requires wrows <= 4096
        if (nb2 > NB2MAX) nb2 = NB2MAX;
    }
    int waves = nb2 * 4;
    // 32-row multiple per wave -> per-wave tile count nt is even (NROWS % 32 == 0)
    int wrows = ((NROWS + waves - 1) / waves + 31) / 32 * 32;

    k_qk<<<16, 256, 0, stream>>>(query, Wq, Wk, qkf, qkb);
    k_score_mm<<<nb2, 256, 0, stream>>>(mem, aw, qkb, cand, nb2, part, wrows);
    k_finalize<<<B, 256, 0, stream>>>(cand, nb2, mem, aw, Wv, part, qkf, out);
}